// Round 9
// baseline (347.378 us; speedup 1.0000x reference)
//
#include <hip/hip_runtime.h>
#include <hip/hip_bf16.h>
#include <math.h>

// ---------------------------------------------------------------------------
// GCN forward. bf16 MFMA GEMMs (LDS-staged W), gather aggregation on bf16
// payload split into two half-row passes (12.8MB gather working set per pass
// for L2 residency). CSR via 128-node micro-partitions.
//   S(bf16) = X@W1 ; Bh(bf16) = relu(agg(S)+b1) ; S = Bh@W2 ;
//   rep(f32) = relu(agg(S)+b2) -> d_out (+ 2-phase e = sigmoid(rep@pw+pb));
//   tau = relu(rep@tw1+tb1)@tw2+tb2 via register-blocked GEMM.
// ---------------------------------------------------------------------------

#define PSZ 128           // nodes per partition (dst-local fits uchar, <128)
#define BIN_CH 16384      // edges per k_bin block (runs of ~21 per bin)

typedef __attribute__((ext_vector_type(8))) short bfrag;   // 8 bf16 (4 VGPR)
typedef __attribute__((ext_vector_type(4))) float ffrag;   // 4 f32 acc

static __device__ __forceinline__ ushort f2bf(float f) {
    __hip_bfloat16 h = __float2bfloat16(f);
    return *reinterpret_cast<ushort*>(&h);
}
static __device__ __forceinline__ float bf2f(ushort u) {
    __hip_bfloat16 h;
    *reinterpret_cast<ushort*>(&h) = u;
    return __bfloat162float(h);
}

// ---------------- CSR build ----------------

// 1) partition histogram: LDS pre-reduce, then one global add per (block,bin)
__global__ __launch_bounds__(256) void k_bhist(const int* __restrict__ edst,
                                               int* __restrict__ bcnt,
                                               int nE, int NB) {
    extern __shared__ int h[];
    const int tid = threadIdx.x;
    const int e0  = blockIdx.x * BIN_CH;
    for (int b = tid; b < NB; b += 256) h[b] = 0;
    __syncthreads();
    for (int i = tid; i < BIN_CH; i += 256) {
        int e = e0 + i;
        if (e < nE) atomicAdd(&h[edst[e] >> 7], 1);
    }
    __syncthreads();
    for (int b = tid; b < NB; b += 256) {
        int v = h[b];
        if (v) atomicAdd(&bcnt[b], v);
    }
}

// 2) one-block scan of bin counts -> bof[] (exclusive), gcur[] init
__global__ __launch_bounds__(1024) void k_bscan(const int* __restrict__ bcnt,
                                                int* __restrict__ bof,
                                                int* __restrict__ gcur,
                                                int NB, int nE) {
    __shared__ int s[1024];
    const int t = threadIdx.x;
    const int v = (t < NB) ? bcnt[t] : 0;
    s[t] = v; __syncthreads();
    for (int o = 1; o < 1024; o <<= 1) {
        int u = (t >= o) ? s[t - o] : 0;
        __syncthreads(); s[t] += u; __syncthreads();
    }
    if (t < NB) { int ex = s[t] - v; bof[t] = ex; gcur[t] = ex; }
    if (t == 0) bof[NB] = nE;
}

// 3) bin edges by partition: per-block LDS hist, one reservation per bin,
//    dense per-(block,bin) runs of pkbin/dlbin
__global__ __launch_bounds__(256) void k_bin(const int* __restrict__ edst,
                                             const int* __restrict__ esrc,
                                             const float* __restrict__ ew,
                                             int* __restrict__ gcur,
                                             unsigned int* __restrict__ pkbin,
                                             unsigned char* __restrict__ dlbin,
                                             int nE, int NB) {
    extern __shared__ int sm[];
    int* hcnt  = sm;            // [NB]
    int* hbase = sm + NB;       // [NB]
    int* hcur  = sm + 2 * NB;   // [NB]
    const int tid = threadIdx.x;
    const int e0  = blockIdx.x * BIN_CH;

    for (int b = tid; b < NB; b += 256) hcnt[b] = 0;
    __syncthreads();
    for (int i = tid; i < BIN_CH; i += 256) {
        int e = e0 + i;
        if (e < nE) atomicAdd(&hcnt[edst[e] >> 7], 1);
    }
    __syncthreads();
    for (int b = tid; b < NB; b += 256) {
        int c = hcnt[b];
        hbase[b] = c ? atomicAdd(&gcur[b], c) : 0;
        hcur[b] = 0;
    }
    __syncthreads();
    for (int i = tid; i < BIN_CH; i += 256) {
        int e = e0 + i;
        if (e < nE) {
            int d = edst[e];
            int p = d >> 7;
            int pos = atomicAdd(&hcur[p], 1);
            int idx = hbase[p] + pos;
            unsigned int w15 = (unsigned int)rintf(ew[e] * 32767.0f);
            pkbin[idx] = (w15 << 17) | (unsigned int)esrc[e];
            dlbin[idx] = (unsigned char)(d & 127);
        }
    }
}

// 4) per-partition placement: ONE block owns one ~8KB spack window.
__global__ __launch_bounds__(256) void k_placepart(
    const unsigned int* __restrict__ pkbin, const unsigned char* __restrict__ dlbin,
    const int* __restrict__ bof, int* __restrict__ off,
    unsigned int* __restrict__ spack, int nN, int NB)
{
    __shared__ int lcnt[PSZ];   // counts, then cursors
    __shared__ int lexc[PSZ];   // exclusive offsets (stable)
    const int tid  = threadIdx.x;
    const int p    = blockIdx.x;
    const int base = bof[p];
    const int tot  = bof[p + 1] - base;

    if (tid < PSZ) lcnt[tid] = 0;
    __syncthreads();
    for (int i = tid; i < tot; i += 256)
        atomicAdd(&lcnt[dlbin[base + i]], 1);
    __syncthreads();
    if (tid < PSZ) lexc[tid] = lcnt[tid];
    __syncthreads();
    for (int o = 1; o < PSZ; o <<= 1) {
        int u = 0;
        if (tid < PSZ && tid >= o) u = lexc[tid - o];
        __syncthreads();
        if (tid < PSZ) lexc[tid] += u;
        __syncthreads();
    }
    if (tid < PSZ) {
        lexc[tid] -= lcnt[tid];          // now exclusive, stable
        int gd = p * PSZ + tid;
        if (gd < nN) off[gd] = base + lexc[tid];
        lcnt[tid] = 0;                   // cursor
    }
    if (p == NB - 1 && tid == 0) off[nN] = base + tot;
    __syncthreads();
    for (int i = tid; i < tot; i += 256) {
        unsigned int pk = pkbin[base + i];
        int dl = dlbin[base + i];
        int r = atomicAdd(&lcnt[dl], 1);
        spack[base + lexc[dl] + r] = pk;
    }
}

// ---------------- weight prep: Wt[n][k] = bf16(W[k][n]) ----------------
__global__ __launch_bounds__(256) void k_prepW(const float* __restrict__ W1,
                                               const float* __restrict__ W2,
                                               ushort* __restrict__ Wt1,
                                               ushort* __restrict__ Wt2) {
    const float* W  = (blockIdx.x == 0) ? W1 : W2;
    ushort*      Wt = (blockIdx.x == 0) ? Wt1 : Wt2;
    for (int j = 0; j < 64; ++j) {
        int idx = threadIdx.x + j * 256;
        int k = idx >> 7, n = idx & 127;
        Wt[n * 128 + k] = f2bf(W[idx]);
    }
}

// ---------------- MFMA GEMM: Y[n,128](bf16) = A[n,128] @ W[128,128] ----------
// 64 rows/block, 4 waves (16 rows x 128 cols each), K=128 in 4 steps of 32.
// A (16KB) and Wt (32KB) both staged to LDS with XOR swizzle (^(row&7)<<4).
template <int ABF16>
__global__ __launch_bounds__(256) void gemm_mfma(
    const void* __restrict__ Av, const ushort* __restrict__ Wt,
    ushort* __restrict__ Y, int nN)
{
    __shared__ ushort Xl[64 * 128];   // 16 KB, swizzled
    __shared__ ushort Wl[128 * 128];  // 32 KB, swizzled
    const int tid  = threadIdx.x;
    const int row0 = blockIdx.x * 64;

    if (ABF16) {
        const int4* X16 = (const int4*)Av;
        #pragma unroll
        for (int j = 0; j < 4; ++j) {
            int u  = tid + j * 256;
            int r  = u >> 4;
            int cb = (u & 15) * 16;
            int grow = row0 + r;
            int4 v = make_int4(0, 0, 0, 0);
            if (grow < nN) v = X16[(size_t)grow * 16 + (u & 15)];
            *(int4*)((char*)Xl + r * 256 + (cb ^ ((r & 7) << 4))) = v;
        }
    } else {
        const float4* X4 = (const float4*)Av;
        #pragma unroll
        for (int j = 0; j < 8; ++j) {
            int u  = tid + j * 256;
            int r  = u >> 5;
            int c4 = (u & 31) * 4;
            int grow = row0 + r;
            float4 v = make_float4(0.f, 0.f, 0.f, 0.f);
            if (grow < nN) v = X4[(size_t)grow * 32 + (u & 31)];
            ushort4 o;
            o.x = f2bf(v.x); o.y = f2bf(v.y); o.z = f2bf(v.z); o.w = f2bf(v.w);
            *(ushort4*)((char*)Xl + r * 256 + ((c4 * 2) ^ ((r & 7) << 4))) = o;
        }
    }
    {   // stage Wt: 2048 int4, same swizzle
        const int4* Wg = (const int4*)Wt;
        #pragma unroll
        for (int j = 0; j < 8; ++j) {
            int u  = tid + j * 256;
            int r  = u >> 4;
            int cb = (u & 15) * 16;
            *(int4*)((char*)Wl + r * 256 + (cb ^ ((r & 7) << 4))) = Wg[u];
        }
    }
    __syncthreads();

    const int lane = tid & 63;
    const int wid  = tid >> 6;
    const int wrow = wid * 16;
    const int arow = wrow + (lane & 15);
    const int kg16 = (lane >> 4) * 16;

    ffrag acc[8];
    #pragma unroll
    for (int ct = 0; ct < 8; ++ct) acc[ct] = (ffrag){0.f, 0.f, 0.f, 0.f};

    #pragma unroll
    for (int ks = 0; ks < 4; ++ks) {
        const int abyte = arow * 256 + ((ks * 64 + kg16) ^ ((arow & 7) << 4));
        bfrag a = *(const bfrag*)((const char*)Xl + abyte);
        #pragma unroll
        for (int ct = 0; ct < 8; ++ct) {
            const int wcol = ct * 16 + (lane & 15);
            const int bbyte = wcol * 256 + ((ks * 64 + kg16) ^ ((wcol & 7) << 4));
            bfrag b = *(const bfrag*)((const char*)Wl + bbyte);
            acc[ct] = __builtin_amdgcn_mfma_f32_16x16x32_bf16(a, b, acc[ct], 0, 0, 0);
        }
    }

    // D layout: col = lane&15, row = (lane>>4)*4 + i
    #pragma unroll
    for (int ct = 0; ct < 8; ++ct) {
        #pragma unroll
        for (int i = 0; i < 4; ++i) {
            int row = row0 + wrow + (lane >> 4) * 4 + i;
            if (row < nN)
                Y[(size_t)row * 128 + ct * 16 + (lane & 15)] = f2bf(acc[ct][i]);
        }
    }
}

// ---------------- gather aggregation, HALF-ROW pass -------------------------
// Processes cols [half*64, half*64+64). 16 lanes/node, ushort4/lane.
// Gather working set = nN*128B = 12.8MB -> L2-friendlier than full rows.
// EPHASE: 0 none; 1 store partial dot(rep_half, pw_half); 2 finalize sigmoid.
template <int EPHASE, int OUTBF>
__global__ __launch_bounds__(256) void k_agg_half(
    const ushort* __restrict__ S, const unsigned int* __restrict__ spack,
    const int* __restrict__ off, const float* __restrict__ bias,
    void* __restrict__ out, const float* __restrict__ pw,
    const float* __restrict__ pb, float* __restrict__ out_e,
    int nN, int half)
{
    const int g      = (blockIdx.x * 256 + threadIdx.x) >> 4;   // node id
    const int lane16 = threadIdx.x & 15;
    if (g >= nN) return;
    const int c  = half * 64 + lane16 * 4;
    const int j0 = off[g], j1 = off[g + 1];

    float4 acc = make_float4(0.f, 0.f, 0.f, 0.f);
    const float wscale = 1.0f / 32767.0f;

    int j = j0;
    for (; j + 8 <= j1; j += 8) {
        unsigned int p[8];
        #pragma unroll
        for (int q = 0; q < 8; ++q) p[q] = spack[j + q];
        ushort4 v[8];
        #pragma unroll
        for (int q = 0; q < 8; ++q)
            v[q] = *(const ushort4*)&S[(size_t)(p[q] & 0x1FFFF) * 128 + c];
        #pragma unroll
        for (int q = 0; q < 8; ++q) {
            const float w = (float)(p[q] >> 17) * wscale;
            acc.x = fmaf(bf2f(v[q].x), w, acc.x);
            acc.y = fmaf(bf2f(v[q].y), w, acc.y);
            acc.z = fmaf(bf2f(v[q].z), w, acc.z);
            acc.w = fmaf(bf2f(v[q].w), w, acc.w);
        }
    }
    for (; j < j1; ++j) {
        const unsigned int p = spack[j];
        const float w = (float)(p >> 17) * wscale;
        const ushort4 v = *(const ushort4*)&S[(size_t)(p & 0x1FFFF) * 128 + c];
        acc.x = fmaf(bf2f(v.x), w, acc.x);
        acc.y = fmaf(bf2f(v.y), w, acc.y);
        acc.z = fmaf(bf2f(v.z), w, acc.z);
        acc.w = fmaf(bf2f(v.w), w, acc.w);
    }

    const float4 bb = ((const float4*)bias)[half * 16 + lane16];
    acc.x = fmaxf(acc.x + bb.x, 0.f);
    acc.y = fmaxf(acc.y + bb.y, 0.f);
    acc.z = fmaxf(acc.z + bb.z, 0.f);
    acc.w = fmaxf(acc.w + bb.w, 0.f);

    if (OUTBF) {
        ushort4 o;
        o.x = f2bf(acc.x); o.y = f2bf(acc.y); o.z = f2bf(acc.z); o.w = f2bf(acc.w);
        *(ushort4*)&((ushort*)out)[(size_t)g * 128 + c] = o;
    } else {
        *(float4*)&((float*)out)[(size_t)g * 128 + c] = acc;
    }

    if (EPHASE) {
        const float4 pv = ((const float4*)pw)[half * 16 + lane16];
        float ep = acc.x * pv.x + acc.y * pv.y + acc.z * pv.z + acc.w * pv.w;
        #pragma unroll
        for (int o = 1; o < 16; o <<= 1) ep += __shfl_xor(ep, o);
        if (lane16 == 0) {
            if (EPHASE == 1) out_e[g] = ep;                       // partial
            else out_e[g] = 1.f / (1.f + expf(-(ep + out_e[g] + pb[0])));
        }
    }
}

// ---------------- tau head: register-blocked GEMM ----------------
__global__ __launch_bounds__(256) void tau_kernel(
    const float* __restrict__ REP, const float* __restrict__ tw1,
    const float* __restrict__ tb1, const float* __restrict__ tw2,
    const float* __restrict__ tb2, float* __restrict__ out_tau, int nN)
{
    __shared__ float Rl[64 * 132];
    __shared__ float Wl[64 * 64];
    __shared__ float stb1[64], stw2[64];

    const int tid  = threadIdx.x;
    const int row0 = blockIdx.x * 64;

    if (tid < 64) { stb1[tid] = tb1[tid]; stw2[tid] = tw2[tid]; }

    #pragma unroll
    for (int j = 0; j < 8; ++j) {
        int i  = tid + j * 256;
        int r  = i >> 5;
        int c4 = i & 31;
        float4 v = make_float4(0.f, 0.f, 0.f, 0.f);
        if (row0 + r < nN) v = ((const float4*)REP)[(size_t)(row0 + r) * 32 + c4];
        ((float4*)Rl)[r * 33 + c4] = v;
    }

    const int cg = tid & 15;
    const int rt = tid >> 4;

    float4 acc[4];
    #pragma unroll
    for (int r = 0; r < 4; ++r) acc[r] = make_float4(0.f, 0.f, 0.f, 0.f);

    for (int kc = 0; kc < 2; ++kc) {
        __syncthreads();
        {
            const float4* s4 = (const float4*)tw1 + kc * 1024;
            #pragma unroll
            for (int j = 0; j < 4; ++j)
                ((float4*)Wl)[tid + j * 256] = s4[tid + j * 256];
        }
        __syncthreads();
        #pragma unroll
        for (int k4 = 0; k4 < 16; ++k4) {
            float4 xr[4];
            #pragma unroll
            for (int r = 0; r < 4; ++r)
                xr[r] = *(const float4*)&Rl[(rt * 4 + r) * 132 + kc * 64 + k4 * 4];
            #pragma unroll
            for (int kk = 0; kk < 4; ++kk) {
                float4 w = *(const float4*)&Wl[(k4 * 4 + kk) * 64 + cg * 4];
                #pragma unroll
                for (int r = 0; r < 4; ++r) {
                    float xv = (kk == 0) ? xr[r].x : (kk == 1) ? xr[r].y
                             : (kk == 2) ? xr[r].z : xr[r].w;
                    acc[r].x = fmaf(xv, w.x, acc[r].x);
                    acc[r].y = fmaf(xv, w.y, acc[r].y);
                    acc[r].z = fmaf(xv, w.z, acc[r].z);
                    acc[r].w = fmaf(xv, w.w, acc[r].w);
                }
            }
        }
    }

    const float4 tb = *(const float4*)&stb1[cg * 4];
    const float4 t2 = *(const float4*)&stw2[cg * 4];
    float taup[4];
    #pragma unroll
    for (int r = 0; r < 4; ++r) {
        float hx = fmaxf(acc[r].x + tb.x, 0.f);
        float hy = fmaxf(acc[r].y + tb.y, 0.f);
        float hz = fmaxf(acc[r].z + tb.z, 0.f);
        float hw = fmaxf(acc[r].w + tb.w, 0.f);
        taup[r] = hx * t2.x + hy * t2.y + hz * t2.z + hw * t2.w;
    }
    #pragma unroll
    for (int o = 1; o < 16; o <<= 1) {
        #pragma unroll
        for (int r = 0; r < 4; ++r) taup[r] += __shfl_xor(taup[r], o);
    }
    if (cg == 0) {
        const float tb2v = tb2[0];
        #pragma unroll
        for (int r = 0; r < 4; ++r) {
            int row = row0 + rt * 4 + r;
            if (row < nN) out_tau[row] = taup[r] + tb2v;
        }
    }
}

// ---------------- launch ----------------
extern "C" void kernel_launch(void* const* d_in, const int* in_sizes, int n_in,
                              void* d_out, int out_size, void* d_ws, size_t ws_size,
                              hipStream_t stream)
{
    const float* x   = (const float*)d_in[0];
    const float* ew  = (const float*)d_in[1];
    const float* W1  = (const float*)d_in[2];
    const float* b1  = (const float*)d_in[3];
    const float* W2  = (const float*)d_in[4];
    const float* b2  = (const float*)d_in[5];
    const float* tw1 = (const float*)d_in[6];
    const float* tb1 = (const float*)d_in[7];
    const float* tw2 = (const float*)d_in[8];
    const float* tb2 = (const float*)d_in[9];
    const float* pw  = (const float*)d_in[10];
    const float* pb  = (const float*)d_in[11];
    const int* esrc  = (const int*)d_in[12];
    const int* edst  = (const int*)d_in[13];

    const int nN = in_sizes[0] / 128;      // 100000
    const int nE = in_sizes[1];            // 1600000
    const int NB = (nN + PSZ - 1) / PSZ;   // 782 partitions

    // workspace carve-up
    char* w = (char*)d_ws;
    ushort*        S     = (ushort*)w;         w += (size_t)nN * 128 * 2;
    ushort*        Bh    = (ushort*)w;         w += (size_t)nN * 128 * 2;
    unsigned int*  spack = (unsigned int*)w;   w += (size_t)nE * 4;
    unsigned int*  pkbin = (unsigned int*)w;   w += (size_t)nE * 4;
    unsigned char* dlbin = (unsigned char*)w;  w += (size_t)nE;
    ushort*        Wt1   = (ushort*)w;         w += 16384 * 2;
    ushort*        Wt2   = (ushort*)w;         w += 16384 * 2;
    int*           off   = (int*)w;            w += (size_t)(nN + 1) * 4;
    int*           bcnt  = (int*)w;            w += (size_t)NB * 4;
    int*           bof   = (int*)w;            w += (size_t)(NB + 1) * 4;
    int*           gcur  = (int*)w;            w += (size_t)NB * 4;

    float* out_tau = (float*)d_out;
    float* out_e   = out_tau + nN;
    float* out_rep = out_e + nN;

    const int binBlocks  = (nE + BIN_CH - 1) / BIN_CH;   // 98
    const int gemmBlocks = (nN + 63) / 64;
    const int aggBlocks  = (nN + 15) / 16;               // 16 nodes/block
    const int tauBlocks  = (nN + 63) / 64;
    const size_t histLds = (size_t)NB * sizeof(int);

    // ---- CSR build (micro-partitioned) ----
    hipMemsetAsync(bcnt, 0, (size_t)NB * sizeof(int), stream);
    k_bhist<<<binBlocks, 256, histLds, stream>>>(edst, bcnt, nE, NB);
    k_bscan<<<1, 1024, 0, stream>>>(bcnt, bof, gcur, NB, nE);
    k_bin<<<binBlocks, 256, 3 * histLds, stream>>>(edst, esrc, ew, gcur,
                                                   pkbin, dlbin, nE, NB);
    k_placepart<<<NB, 256, 0, stream>>>(pkbin, dlbin, bof, off, spack, nN, NB);

    // ---- weight transpose+cast ----
    k_prepW<<<2, 256, 0, stream>>>(W1, W2, Wt1, Wt2);

    // ---- layer 1 ----
    gemm_mfma<0><<<gemmBlocks, 256, 0, stream>>>(x, Wt1, S, nN);
    k_agg_half<0, 1><<<aggBlocks, 256, 0, stream>>>(S, spack, off, b1, Bh,
                                                    nullptr, nullptr, nullptr, nN, 0);
    k_agg_half<0, 1><<<aggBlocks, 256, 0, stream>>>(S, spack, off, b1, Bh,
                                                    nullptr, nullptr, nullptr, nN, 1);

    // ---- layer 2 (rep -> d_out, e in 2 phases) ----
    gemm_mfma<1><<<gemmBlocks, 256, 0, stream>>>(Bh, Wt2, S, nN);
    k_agg_half<1, 0><<<aggBlocks, 256, 0, stream>>>(S, spack, off, b2, out_rep,
                                                    pw, pb, out_e, nN, 0);
    k_agg_half<2, 0><<<aggBlocks, 256, 0, stream>>>(S, spack, off, b2, out_rep,
                                                    pw, pb, out_e, nN, 1);

    // ---- tau head ----
    tau_kernel<<<tauBlocks, 256, 0, stream>>>(out_rep, tw1, tb1, tw2, tb2,
                                              out_tau, nN);
}